// Round 12
// baseline (158.176 us; speedup 1.0000x reference)
//
#include <hip/hip_runtime.h>
#include <math.h>
#include <float.h>
#include <limits.h>

#define TOPK 13
typedef unsigned int u32;
typedef unsigned long long u64;

// ---- numpy-f32-with-FTZ emulation (XLA-CPU style) ----
__device__ __forceinline__ u32 q32f(double x) {
  if (!(x > 0.0)) return 0u;
  float f = (float)x;                       // RTNE
  u32 b = __float_as_uint(f);
  return (b >= 0x00800000u) ? b : 0u;       // FTZ: denormal -> 0
}
__device__ __forceinline__ double val32(u32 b) {
  return (double)__uint_as_float(b);        // b is 0 or normal
}

struct MetricQ { u32 amb; u32 ovb; bool m; };

// FTZ-f32 masked align_metric / overlaps at (b,g,a).  (identical to passing R10/R11)
__device__ MetricQ metric_at(
    const float* __restrict__ pd_scores, const float* __restrict__ pd_bboxes,
    const float* __restrict__ anc, const int* __restrict__ gt_labels,
    const float* __restrict__ gt_bboxes, const float* __restrict__ mask_gt,
    const float* __restrict__ gt_kkpts, const float* __restrict__ pd_kkpts,
    const float* __restrict__ sigma, const float* __restrict__ stride_t,
    int reg_max, int b, int g, int a, int nmax, int na, int nc, int nk)
{
#pragma clang fp contract(off)
  MetricQ r; r.amb = 0u; r.ovb = 0u; r.m = false;
  const float* gb = gt_bboxes + (size_t)(b * nmax + g) * 4;
  float gx1 = gb[0], gy1 = gb[1], gx2 = gb[2], gy2 = gb[3];
  float mgt = mask_gt[b * nmax + g];
  float ax = anc[(size_t)a * 2 + 0], ay = anc[(size_t)a * 2 + 1];
  float dmin = fminf(fminf(ax - gx1, ay - gy1), fminf(gx2 - ax, gy2 - ay));
  float aps = (stride_t[a] * (float)(reg_max - 1)) * 2.0f;
  float gw = gx2 - gx1, gh = gy2 - gy1;
  float gsize = (gw + gh) * 0.5f;
  bool mm = ((double)dmin > 1e-9) && ((double)(aps - gsize) >= 1e-9) && (mgt > 0.f);
  r.m = mm;
  if (!mm) return r;

  int lbl = gt_labels[b * nmax + g];
  float score = pd_scores[((size_t)(b * na + a)) * nc + lbl];

  const float* pb = pd_bboxes + ((size_t)(b * na + a)) * 4;
  float px1 = pb[0], py1 = pb[1], px2 = pb[2], py2 = pb[3];
  const float e7 = 1e-7f;
  float w1 = gx2 - gx1, h1 = (gy2 - gy1) + e7;
  float w2 = px2 - px1, h2 = (py2 - py1) + e7;
  float iw = fmaxf(fminf(gx2, px2) - fmaxf(gx1, px1), 0.f);
  float ih = fmaxf(fminf(gy2, py2) - fmaxf(gy1, py1), 0.f);
  float inter = iw * ih;
  float uni = ((w1 * h1 + w2 * h2) - inter) + e7;
  float iou = inter / uni;
  float cw = fmaxf(gx2, px2) - fminf(gx1, px1);
  float ch = fmaxf(gy2, py2) - fminf(gy1, py1);
  float c2 = (cw * cw + ch * ch) + e7;
  float dcx = ((px1 + px2) - gx1) - gx2;
  float dcy = ((py1 + py2) - gy1) - gy2;
  float rho2 = (dcx * dcx + dcy * dcy) / 4.0f;
  float a2 = (float)atan((double)(w2 / h2));
  float a1 = (float)atan((double)(w1 / h1));
  float arc = a2 - a1;
  const float C = (float)(4.0 / (3.14159265358979323846 * 3.14159265358979323846));
  float v = C * (arc * arc);
  const float C1 = (float)(1.0 + 1e-7);
  float al = v / ((v - iou) + C1);
  float ciou = iou - (rho2 / c2 + v * al);
  float iouc = fmaxf(ciou, 0.f);

  float area = (gw * gh) * 0.53f;
  double ksum = 0.0;
  float  kcnt = 0.f;
  for (int k = 0; k < nk; k++) {
    const float* gk = gt_kkpts + ((size_t)(b * nmax + g) * nk + k) * 3;
    const float* pk = pd_kkpts + (((size_t)(b * na + a)) * nk + k) * 3;
    float km = (gk[2] != 0.f) ? 1.f : 0.f;
    float dx = pk[0] - gk[0], dy = pk[1] - gk[1];
    float d  = dx * dx + dy * dy;
    float s2 = 2.f * sigma[k]; s2 = s2 * s2;
    float e1 = d / s2;
    float e2 = e1 / (area + 1e-7f);
    float e  = e2 / 2.0f;
    double s1 = val32(q32f(exp(-(double)e)));
    double term = s1 * (double)km;
    ksum = val32(q32f(ksum + term));
    kcnt = kcnt + km;
  }
  double den = (double)(kcnt + 1e-7f);
  u32 kioub = q32f(ksum / den);
  double kiou = val32(kioub);
  u32 sumb = q32f((double)iouc + kiou);
  u32 ovlb = q32f(val32(sumb) * 0.5);
  double ovl = val32(ovlb);
  u32 p6b = q32f(pow(ovl, 6.0));
  u32 amb = q32f((double)score * val32(p6b));
  r.ovb = ovlb;
  r.amb = amb;
  return r;
}

__global__ void k_zeroi(int* __restrict__ p, long n) {
  long i = (long)blockIdx.x * blockDim.x + threadIdx.x;
  if (i < n) p[i] = 0;
}

#define MAXC 512   // max in-box anchors per gt (analysis: <= ~305 for this geometry)

// One block per (b,g): candidate compaction -> dense heavy metric ->
// single-wave top-13 (no barriers in selection) -> compact records.
__global__ void k_rows(const float* __restrict__ pd_scores, const float* __restrict__ pd_bboxes,
                       const float* __restrict__ anc, const int* __restrict__ gt_labels,
                       const float* __restrict__ gt_bboxes, const float* __restrict__ mask_gt,
                       const float* __restrict__ gt_kkpts, const float* __restrict__ pd_kkpts,
                       const float* __restrict__ sigma, const float* __restrict__ stride_t,
                       const int* __restrict__ reg_max_p,
                       int* __restrict__ cnt, int* __restrict__ gsel,
                       u32* __restrict__ amsel, u32* __restrict__ ovsel,
                       int bs, int nmax, int na, int nc, int nk)
{
  int g = blockIdx.x, b = blockIdx.y;
  if (mask_gt[b * nmax + g] <= 0.f) return;   // block-uniform, before any barrier
  int reg_max = reg_max_p[0];
  int tid = threadIdx.x;
  int wave = tid >> 6, lane = tid & 63;

  __shared__ int   s_ncand;
  __shared__ int   s_cand[MAXC];
  __shared__ u32   s_keyv[MAXC];
  __shared__ u32   s_ovv[MAXC];
  __shared__ unsigned short s_ciOf[1024];
  __shared__ u32   s_bitPos[32];
  __shared__ int   s_selA[TOPK];
  __shared__ int   s_selCi[TOPK];

  if (tid == 0) s_ncand = 0;
  if (tid < 32) s_bitPos[tid] = 0u;
  for (int i = tid; i < 1024; i += 256) s_ciOf[i] = 0xFFFF;
  __syncthreads();

  // ---- Phase A: cheap in-box mask + compaction ----
  {
    const float* gb = gt_bboxes + (size_t)(b * nmax + g) * 4;
    float gx1 = gb[0], gy1 = gb[1], gx2 = gb[2], gy2 = gb[3];
    float gw = gx2 - gx1, gh = gy2 - gy1;
    float gsize = (gw + gh) * 0.5f;
    for (int a = tid; a < na; a += 256) {
      float ax = anc[(size_t)a * 2 + 0], ay = anc[(size_t)a * 2 + 1];
      float dmin = fminf(fminf(ax - gx1, ay - gy1), fminf(gx2 - ax, gy2 - ay));
      float aps = (stride_t[a] * (float)(reg_max - 1)) * 2.0f;
      bool mm = ((double)dmin > 1e-9) && ((double)(aps - gsize) >= 1e-9);
      if (mm) {
        int ci = atomicAdd(&s_ncand, 1);
        if (ci < MAXC) {
          s_cand[ci] = a;
          if (a < 1024) s_ciOf[a] = (unsigned short)ci;
        }
      }
    }
  }
  __syncthreads();
  int ncand = min(s_ncand, MAXC);

  // ---- Phase B: dense heavy metric over candidates ----
  for (int ci = tid; ci < ncand; ci += 256) {
    int a = s_cand[ci];
    MetricQ mt = metric_at(pd_scores, pd_bboxes, anc, gt_labels, gt_bboxes, mask_gt,
                           gt_kkpts, pd_kkpts, sigma, stride_t, reg_max,
                           b, g, a, nmax, na, nc, nk);
    s_keyv[ci] = mt.amb;
    s_ovv[ci]  = mt.ovb;
    if (mt.amb != 0u && a < 1024) atomicOr(&s_bitPos[a >> 5], 1u << (a & 31));
  }
  __syncthreads();

  // ---- Phase C (wave 0 only, no barriers): top-13 by (key desc, idx asc) ----
  if (wave != 0) return;

  u32 pk = 0xFFFFFFFFu; int pi = -1;
  int npos = TOPK;
  for (int k = 0; k < TOPK; k++) {
    u32 bK = 0u; int bA = INT_MAX; int bCi = -1;
    for (int ci = lane; ci < ncand; ci += 64) {
      u32 vv = s_keyv[ci]; int a = s_cand[ci];
      if (vv < pk || (vv == pk && a > pi)) {          // strictly after previous pick
        if (vv > bK || (vv == bK && a < bA)) { bK = vv; bA = a; bCi = ci; }
      }
    }
    u64 p = ((u64)bK << 32) | (u64)(u32)(0xFFFFFFFFu - (u32)bA);
    u64 w = p;
    for (int off = 32; off; off >>= 1) {
      u64 q = __shfl_xor(w, off);
      if (q > w) w = q;
    }
    u32 wK = (u32)(w >> 32);
    if (wK == 0u) { npos = k; break; }                 // wave-uniform decision
    int wA = (int)(0xFFFFFFFFu - (u32)(w & 0xFFFFFFFFu));
    if (p == w && bCi >= 0 && bK == wK && bA == wA) {  // unique owner lane writes
      s_selCi[k] = bCi; s_selA[k] = wA;
    }
    pk = wK; pi = wA;
  }

  // ---- fills: lowest-index zero-key anchors (mask_pos iff candidate) ----
  if (lane == 0) {
    int a = 0;
    for (int k = npos; k < TOPK; k++) {
      while ((s_bitPos[a >> 5] >> (a & 31)) & 1u) a++;  // skip positive-key anchors
      s_selA[k] = a;
      s_selCi[k] = (s_ciOf[a] == 0xFFFF) ? -1 : (int)s_ciOf[a];
      a++;
    }
  }

  // ---- emission (same wave; LDS within-wave ordering is sufficient) ----
  if (lane < TOPK) {
    int ci = s_selCi[lane];
    if (ci >= 0) {                       // selected AND m==1 -> mask_pos = 1
      int a = s_selA[lane];
      int t = b * na + a;
      atomicAdd(&cnt[t], 1);
      gsel[t] = g;
      amsel[t] = s_keyv[ci];
      ovsel[t] = s_ovv[ci];
    }
  }
}

// Per (b,a): c==0 background, c==1 direct; c>1 appended to multi list.
__global__ void k_anchors(const int* __restrict__ gt_labels, const float* __restrict__ gt_bboxes,
                          const int* __restrict__ cnt, const int* __restrict__ gsel,
                          const u32* __restrict__ amsel, const u32* __restrict__ ovsel,
                          u32* __restrict__ pa, u32* __restrict__ po,
                          u32* __restrict__ amfin, float* __restrict__ out,
                          int* __restrict__ mcount, int* __restrict__ mlist,
                          int bs, int nmax, int na, int nc,
                          long tb_off, long fg_off, long tgi_off)
{
  int t = blockIdx.x * blockDim.x + threadIdx.x;
  if (t >= bs * na) return;
  int b = t / na;

  int c = cnt[t];
  if (c > 1) {
    int i = atomicAdd(mcount, 1);
    mlist[i] = t;
    return;                              // k_multi writes this anchor's outputs
  }
  int tgi = 0; u32 amb = 0u, ovb = 0u; bool fg = false;
  if (c == 1) { tgi = gsel[t]; amb = amsel[t]; ovb = ovsel[t]; fg = true; }

  int lbl = gt_labels[b * nmax + tgi]; if (lbl < 0) lbl = 0;
  out[t] = (float)lbl;
  const float* gb = gt_bboxes + (size_t)(b * nmax + tgi) * 4;
  float* tb = out + tb_off + (long)t * 4;
  tb[0] = gb[0]; tb[1] = gb[1]; tb[2] = gb[2]; tb[3] = gb[3];
  out[fg_off + t] = fg ? 1.0f : 0.0f;
  out[tgi_off + t] = (float)tgi;

  amfin[t] = amb;
  if (fg) {
    int row = b * nmax + tgi;
    atomicMax(&pa[row], amb);
    atomicMax(&po[row], ovb);
  }
}

// One wave per multi-anchor: lane = g; first-argmax of masked overlaps (ties->lowest g).
__global__ void k_multi(const float* __restrict__ pd_scores, const float* __restrict__ pd_bboxes,
                        const float* __restrict__ anc, const int* __restrict__ gt_labels,
                        const float* __restrict__ gt_bboxes, const float* __restrict__ mask_gt,
                        const float* __restrict__ gt_kkpts, const float* __restrict__ pd_kkpts,
                        const float* __restrict__ sigma, const float* __restrict__ stride_t,
                        const int* __restrict__ reg_max_p,
                        const int* __restrict__ mcount, const int* __restrict__ mlist,
                        u32* __restrict__ pa, u32* __restrict__ po,
                        u32* __restrict__ amfin, float* __restrict__ out,
                        int bs, int nmax, int na, int nc, int nk,
                        long tb_off, long fg_off, long tgi_off)
{
  int waveId = (int)((blockIdx.x * blockDim.x + threadIdx.x) >> 6);
  int lane   = threadIdx.x & 63;
  int nwaves = (int)((gridDim.x * blockDim.x) >> 6);
  int reg_max = reg_max_p[0];
  int M = mcount[0];

  for (int i = waveId; i < M; i += nwaves) {
    int t = mlist[i];
    int b = t / na, a = t - b * na;
    u32 ovg = 0u, amg = 0u;
    if (lane < nmax) {
      MetricQ mt = metric_at(pd_scores, pd_bboxes, anc, gt_labels, gt_bboxes, mask_gt,
                             gt_kkpts, pd_kkpts, sigma, stride_t, reg_max,
                             b, lane, a, nmax, na, nc, nk);
      ovg = mt.m ? mt.ovb : 0u;
      amg = mt.m ? mt.amb : 0u;
    }
    u64 p = ((u64)ovg << 32) | (u64)(u32)(0xFFFFFFFFu - (u32)lane);
    for (int off = 32; off; off >>= 1) {
      u64 q = __shfl_xor(p, off);
      if (q > p) p = q;
    }
    int wg = (int)(0xFFFFFFFFu - (u32)(p & 0xFFFFFFFFu));
    if (lane == wg) {                                  // winner lane writes
      int lbl = gt_labels[b * nmax + wg]; if (lbl < 0) lbl = 0;
      out[t] = (float)lbl;
      const float* gb = gt_bboxes + (size_t)(b * nmax + wg) * 4;
      float* tb = out + tb_off + (long)t * 4;
      tb[0] = gb[0]; tb[1] = gb[1]; tb[2] = gb[2]; tb[3] = gb[3];
      out[fg_off + t] = 1.0f;
      out[tgi_off + t] = (float)wg;
      amfin[t] = amg;
      int row = b * nmax + wg;
      atomicMax(&pa[row], amg);
      atomicMax(&po[row], ovg);
    }
  }
}

// Fused zero+scatter: one float4 per (anchor, class-quad); coalesced 43 MB write.
// Reference order: x = q32f(am*po); nrm = q32f(x/(pa+1e-9)).
__global__ void k_fill(const u32* __restrict__ pa, const u32* __restrict__ po,
                       const u32* __restrict__ amfin, float* __restrict__ out,
                       int bs, int nmax, int na, int nc4,
                       long ts_off, long fg_off, long tgi_off)
{
  long idx = (long)blockIdx.x * blockDim.x + threadIdx.x;
  long total = (long)bs * na * nc4;
  if (idx >= total) return;
  int q = (int)(idx % nc4);
  long t = idx / nc4;
  float4 vv = make_float4(0.f, 0.f, 0.f, 0.f);
  if (out[fg_off + t] > 0.f) {
    int lbl = (int)out[t];
    if ((lbl >> 2) == q) {
      int b = (int)(t / na);
      int tgi = (int)out[tgi_off + t];
      int row = b * nmax + tgi;
      u32 xb = q32f(val32(amfin[t]) * val32(po[row]));
      u32 nb = q32f(val32(xb) / (val32(pa[row]) + (double)1e-9f));
      float nrm = __uint_as_float(nb);
      int r = lbl & 3;
      if (r == 0) vv.x = nrm; else if (r == 1) vv.y = nrm;
      else if (r == 2) vv.z = nrm; else vv.w = nrm;
    }
  }
  ((float4*)(out + ts_off))[idx] = vv;
}

extern "C" void kernel_launch(void* const* d_in, const int* in_sizes, int n_in,
                              void* d_out, int out_size, void* d_ws, size_t ws_size,
                              hipStream_t stream) {
  const float* pd_scores = (const float*)d_in[0];
  const float* pd_bboxes = (const float*)d_in[1];
  const float* anc       = (const float*)d_in[2];
  const int*   gt_labels = (const int*)  d_in[3];
  const float* gt_bboxes = (const float*)d_in[4];
  const float* mask_gt   = (const float*)d_in[5];
  const float* gt_kkpts  = (const float*)d_in[6];
  const float* pd_kkpts  = (const float*)d_in[7];
  const float* sigma     = (const float*)d_in[8];
  const float* stride_t  = (const float*)d_in[9];
  const int*   reg_max_p = (const int*)  d_in[10];

  int na   = in_sizes[2] / 2;
  int bs   = in_sizes[1] / (na * 4);
  int nc   = in_sizes[0] / (bs * na);
  int nmax = in_sizes[3] / bs;
  int nk   = in_sizes[8];

  long nba = (long)bs * na;
  int  R   = bs * nmax;

  // ws: [cnt nba][pa R][po R][mcount 64][gsel nba][amsel nba][ovsel nba][amfin nba][mlist nba]
  int* cnt    = (int*)d_ws;
  u32* pa     = (u32*)(cnt + nba);
  u32* po     = pa + R;
  int* mcount = (int*)(po + R);
  int* gsel   = mcount + 64;
  u32* amsel  = (u32*)(gsel + nba);
  u32* ovsel  = amsel + nba;
  u32* amfin  = ovsel + nba;
  int* mlist  = (int*)(amfin + nba);

  float* out = (float*)d_out;
  long tb_off  = nba;
  long ts_off  = nba * 5;
  long fg_off  = ts_off + nba * nc;
  long tgi_off = fg_off + nba;

  long nz = nba + 2L * R + 64;   // cnt + pa + po + mcount
  k_zeroi<<<(int)((nz + 255) / 256), 256, 0, stream>>>(cnt, nz);

  dim3 grows(nmax, bs);
  k_rows<<<grows, 256, 0, stream>>>(pd_scores, pd_bboxes, anc, gt_labels, gt_bboxes,
                                    mask_gt, gt_kkpts, pd_kkpts, sigma, stride_t,
                                    reg_max_p, cnt, gsel, amsel, ovsel,
                                    bs, nmax, na, nc, nk);

  int nthr = (int)((nba + 255) / 256);
  k_anchors<<<nthr, 256, 0, stream>>>(gt_labels, gt_bboxes, cnt, gsel, amsel, ovsel,
                                      pa, po, amfin, out, mcount, mlist,
                                      bs, nmax, na, nc, tb_off, fg_off, tgi_off);

  k_multi<<<256, 256, 0, stream>>>(pd_scores, pd_bboxes, anc, gt_labels, gt_bboxes,
                                   mask_gt, gt_kkpts, pd_kkpts, sigma, stride_t,
                                   reg_max_p, mcount, mlist, pa, po, amfin, out,
                                   bs, nmax, na, nc, nk, tb_off, fg_off, tgi_off);

  int nc4 = nc / 4;
  long totalF4 = nba * nc4;
  k_fill<<<(int)((totalF4 + 255) / 256), 256, 0, stream>>>(pa, po, amfin, out,
                                                           bs, nmax, na, nc4,
                                                           ts_off, fg_off, tgi_off);
}